// Round 1
// baseline (88.726 us; speedup 1.0000x reference)
//
#include <hip/hip_runtime.h>
#include <math.h>

#define NP 196  // 14*14 patches per image
#define FEAT 784

// ---------- Kernel 1: fused conv2x2-stride2 + 4-qubit quantum filter ----------
// One thread per (batch, patch). 16-amplitude real statevector in registers.

__device__ __forceinline__ void apply_ry(float* s, const int mask, float c, float sn) {
#pragma unroll
    for (int i = 0; i < 16; ++i) {
        if (!(i & mask)) {
            float a = s[i], b = s[i | mask];
            s[i]        = c * a - sn * b;
            s[i | mask] = sn * a + c * b;
        }
    }
}

__device__ __forceinline__ void apply_cnot(float* s, const int mc, const int mt) {
#pragma unroll
    for (int i = 0; i < 16; ++i) {
        if ((i & mc) && !(i & mt)) {
            float t = s[i];
            s[i]      = s[i | mt];
            s[i | mt] = t;
        }
    }
}

__global__ void __launch_bounds__(256)
conv_quantum(const float* __restrict__ x,
             const float* __restrict__ cw,   // [4,1,2,2]
             const float* __restrict__ cb,   // [4]
             const float* __restrict__ ang,  // [5]
             float* __restrict__ feats,      // [B, 784] layout: b*784 + c*196 + hw
             int total) {
    int tid = blockIdx.x * blockDim.x + threadIdx.x;
    if (tid >= total) return;
    int b  = tid / NP;
    int hw = tid - b * NP;
    int i  = hw / 14;
    int j  = hw - i * 14;

    const float* xp = x + b * 784 + (2 * i) * 28 + 2 * j;
    float p00 = xp[0], p01 = xp[1], p10 = xp[28], p11 = xp[29];

    // conv angles (encoder thetas), one per qubit/channel
    float cs[4], sn[4];
#pragma unroll
    for (int c = 0; c < 4; ++c) {
        float th = cw[c * 4 + 0] * p00 + cw[c * 4 + 1] * p01 +
                   cw[c * 4 + 2] * p10 + cw[c * 4 + 3] * p11 + cb[c];
        float h = 0.5f * th;
        cs[c] = __cosf(h);
        sn[c] = __sinf(h);
    }

    // |psi> after the 4 encoder RYs on |0000> is a product state:
    // amp(q0..q3) = prod_w (q_w ? sin : cos).  Wire w -> bit (3-w).
    float s[16];
#pragma unroll
    for (int idx = 0; idx < 16; ++idx) {
        float v = (idx & 8 ? sn[0] : cs[0]);
        v      *= (idx & 4 ? sn[1] : cs[1]);
        v      *= (idx & 2 ? sn[2] : cs[2]);
        v      *= (idx & 1 ? sn[3] : cs[3]);
        s[idx] = v;
    }

    // learned layer: RY0, RY1, CNOT(0,1), RY2, CNOT(1,2), RY3, CNOT(2,3), RY0
    float a0 = 0.5f * ang[0], a1 = 0.5f * ang[1], a2 = 0.5f * ang[2],
          a3 = 0.5f * ang[3], a4 = 0.5f * ang[4];
    apply_ry  (s, 8, __cosf(a0), __sinf(a0));   // wire 0
    apply_ry  (s, 4, __cosf(a1), __sinf(a1));   // wire 1
    apply_cnot(s, 8, 4);                        // ctrl 0, tgt 1
    apply_ry  (s, 2, __cosf(a2), __sinf(a2));   // wire 2
    apply_cnot(s, 4, 2);                        // ctrl 1, tgt 2
    apply_ry  (s, 1, __cosf(a3), __sinf(a3));   // wire 3
    apply_cnot(s, 2, 1);                        // ctrl 2, tgt 3
    apply_ry  (s, 8, __cosf(a4), __sinf(a4));   // wire 0

    // <Z_w> = sum probs * (+1 if bit clear else -1)
    float ez0 = 0.f, ez1 = 0.f, ez2 = 0.f, ez3 = 0.f;
#pragma unroll
    for (int idx = 0; idx < 16; ++idx) {
        float p = s[idx] * s[idx];
        ez0 += (idx & 8) ? -p : p;
        ez1 += (idx & 4) ? -p : p;
        ez2 += (idx & 2) ? -p : p;
        ez3 += (idx & 1) ? -p : p;
    }

    float* fo = feats + b * FEAT + hw;
    fo[0 * NP] = ez0;
    fo[1 * NP] = ez1;
    fo[2 * NP] = ez2;
    fo[3 * NP] = ez3;
}

// ---------- Kernel 2: FC (784 -> 10) + log_softmax, one wave per batch row ----

__global__ void __launch_bounds__(256)
fc_lsm(const float* __restrict__ feats,  // [B, 784]
       const float* __restrict__ W,      // [10, 784]
       const float* __restrict__ bias,   // [10]
       float* __restrict__ out,          // [B, 10]
       int B) {
    int gtid = blockIdx.x * blockDim.x + threadIdx.x;
    int row  = gtid >> 6;          // one wave (64 lanes) per batch row
    int lane = threadIdx.x & 63;
    if (row >= B) return;

    const float* f = feats + row * FEAT;
    float acc[10];
#pragma unroll
    for (int k = 0; k < 10; ++k) acc[k] = 0.f;

    for (int t = lane; t < FEAT; t += 64) {
        float v = f[t];
#pragma unroll
        for (int k = 0; k < 10; ++k) acc[k] = fmaf(v, W[k * FEAT + t], acc[k]);
    }

#pragma unroll
    for (int k = 0; k < 10; ++k) {
#pragma unroll
        for (int off = 32; off > 0; off >>= 1)
            acc[k] += __shfl_down(acc[k], off, 64);
    }

    if (lane == 0) {
        float l[10], m = -INFINITY;
#pragma unroll
        for (int k = 0; k < 10; ++k) {
            l[k] = acc[k] + bias[k];
            m = fmaxf(m, l[k]);
        }
        float ssum = 0.f;
#pragma unroll
        for (int k = 0; k < 10; ++k) ssum += __expf(l[k] - m);
        float ls = __logf(ssum) + m;
#pragma unroll
        for (int k = 0; k < 10; ++k) out[row * 10 + k] = l[k] - ls;
    }
}

// ---------- launch ----------

extern "C" void kernel_launch(void* const* d_in, const int* in_sizes, int n_in,
                              void* d_out, int out_size, void* d_ws, size_t ws_size,
                              hipStream_t stream) {
    const float* x      = (const float*)d_in[0];  // [B,1,28,28]
    const float* conv_w = (const float*)d_in[1];  // [4,1,2,2]
    const float* conv_b = (const float*)d_in[2];  // [4]
    const float* angles = (const float*)d_in[3];  // [5]
    const float* fc_w   = (const float*)d_in[4];  // [10,784]
    const float* fc_b   = (const float*)d_in[5];  // [10]
    float* out = (float*)d_out;

    int B = in_sizes[0] / 784;        // 4096
    float* feats = (float*)d_ws;      // needs B*784*4 = ~12.9 MB

    int total = B * NP;
    conv_quantum<<<(total + 255) / 256, 256, 0, stream>>>(x, conv_w, conv_b, angles,
                                                          feats, total);
    fc_lsm<<<(B * 64 + 255) / 256, 256, 0, stream>>>(feats, fc_w, fc_b, out, B);
}

// Round 2
// 82.795 us; speedup vs baseline: 1.0716x; 1.0716x over previous
//
#include <hip/hip_runtime.h>
#include <math.h>

#define NP 196   // 14*14 patches per image
#define FEAT 784

// Fully fused: conv2x2/s2 -> 4-qubit quantum filter -> FC(784->10) -> log_softmax.
// One block per batch image. Phase 1: 196 threads simulate one patch each,
// feats stay in LDS. Phase 2: all 256 threads do the FC + reduction.

__device__ __forceinline__ void apply_ry(float* s, const int mask, float c, float sn) {
#pragma unroll
    for (int i = 0; i < 16; ++i) {
        if (!(i & mask)) {
            float a = s[i], b = s[i | mask];
            s[i]        = c * a - sn * b;
            s[i | mask] = sn * a + c * b;
        }
    }
}

__device__ __forceinline__ void apply_cnot(float* s, const int mc, const int mt) {
#pragma unroll
    for (int i = 0; i < 16; ++i) {
        if ((i & mc) && !(i & mt)) {
            float t = s[i];
            s[i]      = s[i | mt];
            s[i | mt] = t;
        }
    }
}

__global__ void __launch_bounds__(256)
quanv_fused(const float* __restrict__ x,    // [B,1,28,28]
            const float* __restrict__ cw,   // [4,1,2,2]
            const float* __restrict__ cb,   // [4]
            const float* __restrict__ ang,  // [5]
            const float* __restrict__ W,    // [10,784]
            const float* __restrict__ bias, // [10]
            float* __restrict__ out) {      // [B,10]
    __shared__ float feats[FEAT];
    __shared__ float partial[4 * 10];   // 4 waves x 10 classes

    const int b   = blockIdx.x;
    const int tid = threadIdx.x;

    // ---------------- Phase 1: quantum filter for patches ----------------
    if (tid < NP) {
        const int i = tid / 14;
        const int j = tid - i * 14;

        const float* xp = x + b * 784 + (2 * i) * 28 + 2 * j;
        const float2 r0 = *(const float2*)(xp);
        const float2 r1 = *(const float2*)(xp + 28);

        float cs[4], sn[4];
#pragma unroll
        for (int c = 0; c < 4; ++c) {
            float th = cw[c * 4 + 0] * r0.x + cw[c * 4 + 1] * r0.y +
                       cw[c * 4 + 2] * r1.x + cw[c * 4 + 3] * r1.y + cb[c];
            float h = 0.5f * th;
            cs[c] = __cosf(h);
            sn[c] = __sinf(h);
        }

        // product state after encoder RYs: bit3=q0, bit2=q1, bit1=q2, bit0=q3
        float s[16];
        {
            float v00 = cs[0] * cs[1], v01 = cs[0] * sn[1];
            float v10 = sn[0] * cs[1], v11 = sn[0] * sn[1];
            float w00 = cs[2] * cs[3], w01 = cs[2] * sn[3];
            float w10 = sn[2] * cs[3], w11 = sn[2] * sn[3];
            s[ 0] = v00 * w00; s[ 1] = v00 * w01; s[ 2] = v00 * w10; s[ 3] = v00 * w11;
            s[ 4] = v01 * w00; s[ 5] = v01 * w01; s[ 6] = v01 * w10; s[ 7] = v01 * w11;
            s[ 8] = v10 * w00; s[ 9] = v10 * w01; s[10] = v10 * w10; s[11] = v10 * w11;
            s[12] = v11 * w00; s[13] = v11 * w01; s[14] = v11 * w10; s[15] = v11 * w11;
        }

        // learned layer: RY0, RY1, CNOT(0,1), RY2, CNOT(1,2), RY3, CNOT(2,3), RY0
        float a0 = 0.5f * ang[0], a1 = 0.5f * ang[1], a2 = 0.5f * ang[2],
              a3 = 0.5f * ang[3], a4 = 0.5f * ang[4];
        apply_ry  (s, 8, __cosf(a0), __sinf(a0));
        apply_ry  (s, 4, __cosf(a1), __sinf(a1));
        apply_cnot(s, 8, 4);
        apply_ry  (s, 2, __cosf(a2), __sinf(a2));
        apply_cnot(s, 4, 2);
        apply_ry  (s, 1, __cosf(a3), __sinf(a3));
        apply_cnot(s, 2, 1);
        apply_ry  (s, 8, __cosf(a4), __sinf(a4));

        float ez0 = 0.f, ez1 = 0.f, ez2 = 0.f, ez3 = 0.f;
#pragma unroll
        for (int idx = 0; idx < 16; ++idx) {
            float p = s[idx] * s[idx];
            ez0 += (idx & 8) ? -p : p;
            ez1 += (idx & 4) ? -p : p;
            ez2 += (idx & 2) ? -p : p;
            ez3 += (idx & 1) ? -p : p;
        }

        feats[0 * NP + tid] = ez0;
        feats[1 * NP + tid] = ez1;
        feats[2 * NP + tid] = ez2;
        feats[3 * NP + tid] = ez3;
    }

    __syncthreads();

    // ---------------- Phase 2: FC 784 -> 10 + log_softmax ----------------
    float acc[10];
#pragma unroll
    for (int k = 0; k < 10; ++k) acc[k] = 0.f;

    for (int t = tid; t < FEAT; t += 256) {
        float v = feats[t];
#pragma unroll
        for (int k = 0; k < 10; ++k) acc[k] = fmaf(v, W[k * FEAT + t], acc[k]);
    }

    // wave-level reduce
#pragma unroll
    for (int k = 0; k < 10; ++k) {
#pragma unroll
        for (int off = 32; off > 0; off >>= 1)
            acc[k] += __shfl_down(acc[k], off, 64);
    }
    const int wave = tid >> 6;
    const int lane = tid & 63;
    if (lane == 0) {
#pragma unroll
        for (int k = 0; k < 10; ++k) partial[wave * 10 + k] = acc[k];
    }
    __syncthreads();

    if (tid == 0) {
        float l[10], m = -INFINITY;
#pragma unroll
        for (int k = 0; k < 10; ++k) {
            l[k] = partial[k] + partial[10 + k] + partial[20 + k] + partial[30 + k] + bias[k];
            m = fmaxf(m, l[k]);
        }
        float ssum = 0.f;
#pragma unroll
        for (int k = 0; k < 10; ++k) ssum += __expf(l[k] - m);
        float ls = __logf(ssum) + m;
        float* o = out + b * 10;
#pragma unroll
        for (int k = 0; k < 10; ++k) o[k] = l[k] - ls;
    }
}

extern "C" void kernel_launch(void* const* d_in, const int* in_sizes, int n_in,
                              void* d_out, int out_size, void* d_ws, size_t ws_size,
                              hipStream_t stream) {
    const float* x      = (const float*)d_in[0];
    const float* conv_w = (const float*)d_in[1];
    const float* conv_b = (const float*)d_in[2];
    const float* angles = (const float*)d_in[3];
    const float* fc_w   = (const float*)d_in[4];
    const float* fc_b   = (const float*)d_in[5];
    float* out = (float*)d_out;

    int B = in_sizes[0] / 784;  // 4096
    quanv_fused<<<B, 256, 0, stream>>>(x, conv_w, conv_b, angles, fc_w, fc_b, out);
}